// Round 3
// baseline (572.127 us; speedup 1.0000x reference)
//
#include <hip/hip_runtime.h>
#include <hip/hip_fp16.h>

// GCN 2-layer forward on MI355X (gfx950).
// conv(x,W,b)[v] = dinv[v]*( sum_{(u,v)} g[u] + g[v] ) + b,  g[u]=dinv[u]*(x[u]@W)
// gemm1 = MFMA bf16 3-term split (~fp32 accuracy); aggregation = CSR gather with
// fp16 message buffers; layer-2 GEMM fused into gather1; log_softmax fused into
// gather2. Round-9: DEGREE-SORTED vertex assignment (counting sort by degree)
// so each wave's 4/8 vertex-groups have equal CSR trip counts -> divergence
// waste ~20-26% -> ~2%. Gathers keep 16/8-lane groups, 8B row-slices.

#define IN_DIM 512
#define HID    64
#define OUTD   32

typedef __attribute__((ext_vector_type(8))) short bf16x8;
typedef __attribute__((ext_vector_type(4))) float floatx4;
typedef __attribute__((ext_vector_type(4))) unsigned short ushort4v;
typedef __attribute__((ext_vector_type(8))) unsigned short ushort8v;

__device__ __forceinline__ unsigned short f2bf(float f) {
    unsigned int u = __float_as_uint(f);
    unsigned int r = (u + 0x7fffu + ((u >> 16) & 1u)) >> 16;
    return (unsigned short)r;
}
__device__ __forceinline__ float bf2f(unsigned short h) {
    return __uint_as_float(((unsigned int)h) << 16);
}

// load 4 consecutive halves (8B, one dwordx2) -> float4
__device__ __forceinline__ float4 ld4h(const __half* p) {
    uint2 u = *(const uint2*)(p);
    __half2 a = *(__half2*)&u.x, b = *(__half2*)&u.y;
    float2 fa = __half22float2(a), fb = __half22float2(b);
    return make_float4(fa.x, fa.y, fb.x, fb.y);
}

__device__ __forceinline__ int eidx(const int* idx32, long long e, int is64) {
    if (is64) { const long long* p = (const long long*)idx32; return (int)p[e]; }
    return idx32[e];
}

// --- fused init: cnt zero + hist zero + int64 detect + W1 transpose/split ----
__global__ void k_init(const float* __restrict__ W1,
                       unsigned short* __restrict__ W1t_hi,
                       unsigned short* __restrict__ W1t_lo,
                       const int* __restrict__ idx, int* __restrict__ flag,
                       int* __restrict__ cnt, int* __restrict__ hist, int N) {
    int t = blockIdx.x * blockDim.x + threadIdx.x;
    if (t == 0) {
        int z = (idx[1] == 0) & (idx[3] == 0) & (idx[5] == 0) & (idx[7] == 0);
        *flag = z;
    }
    if (t < 256) hist[t] = 0;
    if (t < N) cnt[t] = 0;
    if (t < 64 * 512) {
        int n = t >> 9, k = t & 511;
        float v = W1[k * HID + n];
        unsigned short h = f2bf(v);
        W1t_hi[t] = h;
        W1t_lo[t] = f2bf(v - bf2f(h));
    }
}

__global__ void k_count(const int* __restrict__ idx, const int* __restrict__ flag,
                        int* __restrict__ cnt, int E) {
    int e = blockIdx.x * blockDim.x + threadIdx.x;
    if (e >= E) return;
    const int is64 = *flag;
    int c = eidx(idx, (long long)E + e, is64);
    atomicAdd(&cnt[c], 1);
}

// --- parallel 3-kernel exclusive scan; dinv folded into scanA ----------------
__global__ void k_scanA(const int* __restrict__ cnt, int* __restrict__ rowptr,
                        int* __restrict__ part, float* __restrict__ dinv, int N) {
    __shared__ int s[256];
    const int t = threadIdx.x;
    const int i = blockIdx.x * 256 + t;
    int v = (i < N) ? cnt[i] : 0;
    if (i < N) dinv[i] = rsqrtf((float)(1 + v));
    s[t] = v;
    __syncthreads();
#pragma unroll
    for (int off = 1; off < 256; off <<= 1) {
        int x = (t >= off) ? s[t - off] : 0;
        __syncthreads();
        s[t] += x;
        __syncthreads();
    }
    if (i < N) rowptr[i] = s[t] - v;
    if (t == 255) part[blockIdx.x] = s[255];
}

__global__ void k_scanB(const int* __restrict__ part, int* __restrict__ partex, int nb) {
    __shared__ int s[1024];
    const int t = threadIdx.x;
    int v = (t < nb) ? part[t] : 0;
    s[t] = v;
    __syncthreads();
#pragma unroll
    for (int off = 1; off < 1024; off <<= 1) {
        int x = (t >= off) ? s[t - off] : 0;
        __syncthreads();
        s[t] += x;
        __syncthreads();
    }
    partex[t] = s[t] - v;
}

// scanC + per-block degree histogram (LDS-aggregated)
__global__ void k_scanC(int* __restrict__ rowptr, const int* __restrict__ partex,
                        const int* __restrict__ cnt, int* __restrict__ hist,
                        int N, int E) {
    __shared__ int lh[256];
    const int t = threadIdx.x;
    const int i = blockIdx.x * 256 + t;
    lh[t] = 0;
    __syncthreads();
    if (i < N) {
        rowptr[i] += partex[i >> 8];
        atomicAdd(&lh[min(cnt[i], 255)], 1);
    }
    if (i == 0) rowptr[N] = E;
    __syncthreads();
    int c = lh[t];
    if (c) atomicAdd(&hist[t], c);
}

// exclusive scan of the 256-bin degree histogram
__global__ void k_binscan(const int* __restrict__ hist, int* __restrict__ binofs) {
    __shared__ int s[256];
    const int t = threadIdx.x;
    int v = hist[t];
    s[t] = v;
    __syncthreads();
#pragma unroll
    for (int off = 1; off < 256; off <<= 1) {
        int x = (t >= off) ? s[t - off] : 0;
        __syncthreads();
        s[t] += x;
        __syncthreads();
    }
    binofs[t] = s[t] - v;
}

// counting-sort placement: perm holds vertex ids in ascending-degree order
__global__ void k_permplace(const int* __restrict__ cnt, int* __restrict__ binofs,
                            int* __restrict__ perm, int N) {
    __shared__ int lh[256];
    __shared__ int lbase[256];
    const int t = threadIdx.x;
    const int v = blockIdx.x * 256 + t;
    lh[t] = 0;
    __syncthreads();
    int d = 0, my = 0;
    if (v < N) {
        d = min(cnt[v], 255);
        my = atomicAdd(&lh[d], 1);
    }
    __syncthreads();
    int c = lh[t];
    if (c) lbase[t] = atomicAdd(&binofs[t], c);
    __syncthreads();
    if (v < N) perm[lbase[d] + my] = v;
}

__global__ void k_place(const int* __restrict__ idx, const int* __restrict__ flag,
                        int* __restrict__ cnt, const int* __restrict__ rowptr,
                        int* __restrict__ src, int E) {
    int e = blockIdx.x * blockDim.x + threadIdx.x;
    if (e >= E) return;
    const int is64 = *flag;
    int r = eidx(idx, e, is64);
    int c = eidx(idx, (long long)E + e, is64);
    int ofs = atomicAdd(&cnt[c], -1) - 1;
    src[rowptr[c] + ofs] = r;
}

// --- layer-1 GEMM via MFMA: g1[r][j] = fp16( dinv[r]*(x[r]@W1)[j] ) ----------
// (known-good 592us version: LDS-staged x and W hi/lo planes)
__launch_bounds__(256)
__global__ void k_gemm1_mfma(const float* __restrict__ x,
                             const unsigned short* __restrict__ Wt_hi,
                             const unsigned short* __restrict__ Wt_lo,
                             const float* __restrict__ dinv,
                             __half* __restrict__ g1, int N) {
    __shared__ unsigned short xs_hi[64 * 72];
    __shared__ unsigned short xs_lo[64 * 72];
    __shared__ unsigned short ws_hi[64 * 72];
    __shared__ unsigned short ws_lo[64 * 72];

    const int t = threadIdx.x;
    const int lane = t & 63;
    const int w = t >> 6;
    const int m = lane & 15;
    const int quad = lane >> 4;
    const int row_base = blockIdx.x * 64;

    const floatx4 zero = {0.0f, 0.0f, 0.0f, 0.0f};
    floatx4 acc[4] = {zero, zero, zero, zero};

    for (int kc = 0; kc < IN_DIM; kc += 64) {
        {   // stage x: 64 rows x 64 k -> bf16 hi/lo
            const int kq = (t & 15) * 4;
#pragma unroll
            for (int p = 0; p < 4; ++p) {
                int rl = (t >> 4) + p * 16;
                int row = row_base + rl;
                if (row > N - 1) row = N - 1;
                float4 v = *(const float4*)(x + (size_t)row * IN_DIM + kc + kq);
                ushort4v hi, lo;
                hi.x = f2bf(v.x); lo.x = f2bf(v.x - bf2f(hi.x));
                hi.y = f2bf(v.y); lo.y = f2bf(v.y - bf2f(hi.y));
                hi.z = f2bf(v.z); lo.z = f2bf(v.z - bf2f(hi.z));
                hi.w = f2bf(v.w); lo.w = f2bf(v.w - bf2f(hi.w));
                *(ushort4v*)&xs_hi[rl * 72 + kq] = hi;
                *(ushort4v*)&xs_lo[rl * 72 + kq] = lo;
            }
        }
        {   // stage W: 64 n x 64 k (each thread 1 n x 16 k, 2x ushort8v per plane)
            const int nl = t >> 2;
            const int q = (t & 3) * 16;
            const unsigned short* ph = Wt_hi + (size_t)nl * IN_DIM + kc + q;
            const unsigned short* pl = Wt_lo + (size_t)nl * IN_DIM + kc + q;
            *(ushort8v*)&ws_hi[nl * 72 + q]     = *(const ushort8v*)(ph);
            *(ushort8v*)&ws_hi[nl * 72 + q + 8] = *(const ushort8v*)(ph + 8);
            *(ushort8v*)&ws_lo[nl * 72 + q]     = *(const ushort8v*)(pl);
            *(ushort8v*)&ws_lo[nl * 72 + q + 8] = *(const ushort8v*)(pl + 8);
        }
        __syncthreads();
#pragma unroll
        for (int ks = 0; ks < 2; ++ks) {
            const int ko = ks * 32 + quad * 8;
            bf16x8 a_hi = *(const bf16x8*)&xs_hi[(w * 16 + m) * 72 + ko];
            bf16x8 a_lo = *(const bf16x8*)&xs_lo[(w * 16 + m) * 72 + ko];
#pragma unroll
            for (int nt = 0; nt < 4; ++nt) {
                bf16x8 b_hi = *(const bf16x8*)&ws_hi[(nt * 16 + m) * 72 + ko];
                bf16x8 b_lo = *(const bf16x8*)&ws_lo[(nt * 16 + m) * 72 + ko];
                acc[nt] = __builtin_amdgcn_mfma_f32_16x16x32_bf16(a_hi, b_hi, acc[nt], 0, 0, 0);
                acc[nt] = __builtin_amdgcn_mfma_f32_16x16x32_bf16(a_lo, b_hi, acc[nt], 0, 0, 0);
                acc[nt] = __builtin_amdgcn_mfma_f32_16x16x32_bf16(a_hi, b_lo, acc[nt], 0, 0, 0);
            }
        }
        __syncthreads();
    }
    // D layout: col = lane&15, row = quad*4 + r
#pragma unroll
    for (int r = 0; r < 4; ++r) {
        const int row = row_base + w * 16 + quad * 4 + r;
        if (row < N) {
            const float dv = dinv[row];
#pragma unroll
            for (int nt = 0; nt < 4; ++nt)
                g1[(size_t)row * HID + nt * 16 + m] = __float2half(acc[nt][r] * dv);
        }
    }
}

// --- fused layer-1 aggregate + layer-2 GEMM (degree-sorted via perm) ---------
// 16 lanes per vertex, 8B (4-half) loads; 4 vertices/wave with EQUAL degrees.
__launch_bounds__(256)
__global__ void k_agg1_gemm2(const int* __restrict__ rowptr, const int* __restrict__ src,
                             const int* __restrict__ perm,
                             const __half* __restrict__ g1, const float* __restrict__ W2,
                             const float* __restrict__ b1, const float* __restrict__ dinv,
                             __half* __restrict__ g2, int N) {
    __shared__ float w2s[HID * OUTD];   // 8 KB
    __shared__ float hs[16][HID];       // 4 KB
    __shared__ float sdv[16];
    __shared__ int   svid[16];

    const int t = threadIdx.x;
    for (int i = t; i < HID * OUTD; i += 256) w2s[i] = W2[i];

    const int wv = t >> 6, lane = t & 63;
    const int grp = lane >> 4;          // 4 vertex-groups per wave
    const int l16 = lane & 15;
    const int vl = wv * 4 + grp;        // local vertex slot 0..15
    const int idxv = blockIdx.x * 16 + vl;
    const int v = (idxv < N) ? perm[idxv] : -1;
    const int c0 = l16 * 4;             // this lane's 4 columns

    if (v >= 0) {
        float4 acc = ld4h(g1 + (size_t)v * HID + c0);   // self-loop
        int i = rowptr[v];
        const int end = rowptr[v + 1];
        for (; i + 3 < end; i += 4) {
            int r0 = src[i], r1 = src[i + 1], r2 = src[i + 2], r3 = src[i + 3];
            float4 a0 = ld4h(g1 + (size_t)r0 * HID + c0);
            float4 a1 = ld4h(g1 + (size_t)r1 * HID + c0);
            float4 a2 = ld4h(g1 + (size_t)r2 * HID + c0);
            float4 a3 = ld4h(g1 + (size_t)r3 * HID + c0);
            acc.x += (a0.x + a1.x) + (a2.x + a3.x);
            acc.y += (a0.y + a1.y) + (a2.y + a3.y);
            acc.z += (a0.z + a1.z) + (a2.z + a3.z);
            acc.w += (a0.w + a1.w) + (a2.w + a3.w);
        }
        for (; i < end; ++i) {
            float4 a = ld4h(g1 + (size_t)src[i] * HID + c0);
            acc.x += a.x; acc.y += a.y; acc.z += a.z; acc.w += a.w;
        }
        const float dv = dinv[v];
        const float4 b = *(const float4*)(b1 + c0);
        float4 h;
        h.x = fmaxf(fmaf(dv, acc.x, b.x), 0.0f);
        h.y = fmaxf(fmaf(dv, acc.y, b.y), 0.0f);
        h.z = fmaxf(fmaf(dv, acc.z, b.z), 0.0f);
        h.w = fmaxf(fmaf(dv, acc.w, b.w), 0.0f);
        *(float4*)&hs[vl][c0] = h;
        if (l16 == 0) { sdv[vl] = dv; svid[vl] = v; }
    } else if (l16 == 0) {
        svid[vl] = -1;
    }
    __syncthreads();   // covers w2s staging AND hs rows
    // 16 vertices x 32 outputs = 512; each thread does 2.
#pragma unroll
    for (int hh = 0; hh < 2; ++hh) {
        const int o = hh * 256 + t;
        const int vert = o >> 5;        // 0..15 (broadcast within 32-lane group)
        const int j = o & 31;
        const int gv = svid[vert];
        if (gv >= 0) {
            float s = 0.0f;
#pragma unroll
            for (int k = 0; k < HID; ++k) s = fmaf(hs[vert][k], w2s[k * OUTD + j], s);
            g2[(size_t)gv * OUTD + j] = __float2half(s * sdv[vert]);
        }
    }
}

// --- fused layer-2 aggregate + bias + log_softmax (degree-sorted) ------------
// 8 lanes per vertex; 8 vertices/wave with EQUAL degrees; 32 rows in flight.
__global__ void k_out(const int* __restrict__ rowptr, const int* __restrict__ src,
                      const int* __restrict__ perm,
                      const __half* __restrict__ g2, const float* __restrict__ b2,
                      const float* __restrict__ dinv, float* __restrict__ out, int N) {
    const int t = threadIdx.x;
    const int wv = t >> 6, lane = t & 63;
    const int grp = lane >> 3;          // 8 vertex-groups per wave
    const int l8 = lane & 7;
    const int idxv = blockIdx.x * 32 + wv * 8 + grp;
    if (idxv >= N) return;
    const int v = perm[idxv];
    const int c0 = l8 * 4;              // this lane's 4 columns

    float4 acc = ld4h(g2 + (size_t)v * OUTD + c0);   // self-loop
    int i = rowptr[v];
    const int end = rowptr[v + 1];
    for (; i + 3 < end; i += 4) {
        int r0 = src[i], r1 = src[i + 1], r2 = src[i + 2], r3 = src[i + 3];
        float4 a0 = ld4h(g2 + (size_t)r0 * OUTD + c0);
        float4 a1 = ld4h(g2 + (size_t)r1 * OUTD + c0);
        float4 a2 = ld4h(g2 + (size_t)r2 * OUTD + c0);
        float4 a3 = ld4h(g2 + (size_t)r3 * OUTD + c0);
        acc.x += (a0.x + a1.x) + (a2.x + a3.x);
        acc.y += (a0.y + a1.y) + (a2.y + a3.y);
        acc.z += (a0.z + a1.z) + (a2.z + a3.z);
        acc.w += (a0.w + a1.w) + (a2.w + a3.w);
    }
    for (; i < end; ++i) {
        float4 a = ld4h(g2 + (size_t)src[i] * OUTD + c0);
        acc.x += a.x; acc.y += a.y; acc.z += a.z; acc.w += a.w;
    }
    const float dv = dinv[v];
    const float4 b = *(const float4*)(b2 + c0);
    float4 z;
    z.x = fmaf(dv, acc.x, b.x);
    z.y = fmaf(dv, acc.y, b.y);
    z.z = fmaf(dv, acc.z, b.z);
    z.w = fmaf(dv, acc.w, b.w);
    float m = fmaxf(fmaxf(z.x, z.y), fmaxf(z.z, z.w));
#pragma unroll
    for (int d = 1; d < 8; d <<= 1) m = fmaxf(m, __shfl_xor(m, d, 64));
    float s = expf(z.x - m) + expf(z.y - m) + expf(z.z - m) + expf(z.w - m);
#pragma unroll
    for (int d = 1; d < 8; d <<= 1) s += __shfl_xor(s, d, 64);
    const float ml = m + logf(s);
    float4 o;
    o.x = z.x - ml; o.y = z.y - ml; o.z = z.z - ml; o.w = z.w - ml;
    *(float4*)(out + (size_t)v * OUTD + c0) = o;
}

extern "C" void kernel_launch(void* const* d_in, const int* in_sizes, int n_in,
                              void* d_out, int out_size, void* d_ws, size_t ws_size,
                              hipStream_t stream) {
    const float* x   = (const float*)d_in[0];
    const int*   idx = (const int*)d_in[1];
    const float* W1  = (const float*)d_in[2];
    const float* b1  = (const float*)d_in[3];
    const float* W2  = (const float*)d_in[4];
    const float* b2  = (const float*)d_in[5];
    float* out = (float*)d_out;

    const int N = in_sizes[0] / IN_DIM;      // 100000
    const int E = in_sizes[1] / 2;           // 1600000

    // ---- workspace layout ----
    unsigned short* W1t_hi = (unsigned short*)d_ws;        // 64*512
    unsigned short* W1t_lo = W1t_hi + 64 * 512;
    int* cnt    = (int*)(W1t_lo + 64 * 512);               // N
    int* rowptr = cnt + N;                                 // N+4
    int* part   = rowptr + (N + 4);                        // 1024
    int* partex = part + 1024;                             // 1024
    int* hist   = partex + 1024;                           // 256
    int* binofs = hist + 256;                              // 256
    int* perm   = binofs + 256;                            // N
    int* srcA   = perm + N;                                // E
    int* flag   = srcA + E;                                // 4
    float* dinv = (float*)(flag + 4);                      // N
    __half* g1  = (__half*)(dinv + N);                     // 64N halves
    __half* g2  = g1 + (size_t)N * HID;                    // 32N halves

    const int B = 256;
    const int nb = (N + 255) / 256;

    k_init<<<(N + B - 1) / B, B, 0, stream>>>(W1, W1t_hi, W1t_lo, idx, flag, cnt, hist, N);
    k_count<<<(E + B - 1) / B, B, 0, stream>>>(idx, flag, cnt, E);
    k_scanA<<<nb, 256, 0, stream>>>(cnt, rowptr, part, dinv, N);
    k_scanB<<<1, 1024, 0, stream>>>(part, partex, nb);
    k_scanC<<<nb, 256, 0, stream>>>(rowptr, partex, cnt, hist, N, E);
    k_binscan<<<1, 256, 0, stream>>>(hist, binofs);
    k_permplace<<<nb, 256, 0, stream>>>(cnt, binofs, perm, N);
    k_place<<<(E + B - 1) / B, B, 0, stream>>>(idx, flag, cnt, rowptr, srcA, E);

    k_gemm1_mfma<<<(N + 63) / 64, 256, 0, stream>>>(x, W1t_hi, W1t_lo, dinv, g1, N);
    k_agg1_gemm2<<<(N + 15) / 16, 256, 0, stream>>>(rowptr, srcA, perm, g1, W2, b1, dinv, g2, N);
    k_out<<<(N + 31) / 32, B, 0, stream>>>(rowptr, srcA, perm, g2, b2, dinv, out, N);
}